// Round 9
// baseline (410.724 us; speedup 1.0000x reference)
//
#include <hip/hip_runtime.h>

typedef short bf16x8 __attribute__((ext_vector_type(8)));
typedef float f32x4 __attribute__((ext_vector_type(4)));
typedef float f32x16 __attribute__((ext_vector_type(16)));

__device__ __forceinline__ ushort f2bf(float f) {
    union { float f; unsigned u; } v; v.f = f;
    unsigned r = (v.u + 0x7fffu + ((v.u >> 16) & 1u)) >> 16;
    return (ushort)r;
}
__device__ __forceinline__ float bf2f(ushort u) {
    union { unsigned u; float f; } v; v.u = ((unsigned)u) << 16;
    return v.f;
}
__device__ __forceinline__ void async_copy16(void* lds, const void* g) {
    __builtin_amdgcn_global_load_lds(
        (const __attribute__((address_space(1))) unsigned*)g,
        (__attribute__((address_space(3))) unsigned*)lds, 16, 0, 0);
}
// raw barriers: never drain vmcnt (the __syncthreads structural stall)
#define BAR_NONE() asm volatile("s_barrier" ::: "memory")
#define BAR_LGKM() asm volatile("s_waitcnt lgkmcnt(0)\n\ts_barrier" ::: "memory")

// ---------------- fp32 -> bf16 conversion (weights) ----------------
__global__ __launch_bounds__(256)
void cvt_f32_bf16(const float* __restrict__ src, ushort* __restrict__ dst, int n) {
    int i = (blockIdx.x * 256 + threadIdx.x) * 4;
    if (i >= n) return;
    float4 v = *(const float4*)(src + i);
    ushort4 o;
    o.x = f2bf(v.x); o.y = f2bf(v.y); o.z = f2bf(v.z); o.w = f2bf(v.w);
    *(ushort4*)(dst + i) = o;
}

// ---------------- transpose-convert 512x512 fp32 -> bf16 ----------------
__global__ __launch_bounds__(256)
void cvt_wT(const float* __restrict__ in0, const float* __restrict__ in1,
            ushort* __restrict__ out0, ushort* __restrict__ out1)
{
    const float* in = blockIdx.z ? in1 : in0;
    ushort* out     = blockIdx.z ? out1 : out0;
    __shared__ ushort T[64][72];
    const int r0 = blockIdx.y * 64, c0 = blockIdx.x * 64;
    const int t = threadIdx.x;
    const int rr = t >> 3, cc8 = (t & 7) * 8;
    #pragma unroll
    for (int pass = 0; pass < 2; ++pass) {
        int r = rr + pass * 32;
        float4 a = *(const float4*)(in + (size_t)(r0 + r) * 512 + c0 + cc8);
        float4 bq = *(const float4*)(in + (size_t)(r0 + r) * 512 + c0 + cc8 + 4);
        T[r][cc8+0]=f2bf(a.x);  T[r][cc8+1]=f2bf(a.y);  T[r][cc8+2]=f2bf(a.z);  T[r][cc8+3]=f2bf(a.w);
        T[r][cc8+4]=f2bf(bq.x); T[r][cc8+5]=f2bf(bq.y); T[r][cc8+6]=f2bf(bq.z); T[r][cc8+7]=f2bf(bq.w);
    }
    __syncthreads();
    const int c = t >> 2, seg = (t & 3) * 16;
    ushort tmp[16];
    #pragma unroll
    for (int j = 0; j < 16; ++j) tmp[j] = T[seg + j][c];
    *(uint4*)(out + (size_t)(c0 + c) * 512 + r0 + seg)     = *(uint4*)&tmp[0];
    *(uint4*)(out + (size_t)(c0 + c) * 512 + r0 + seg + 8) = *(uint4*)&tmp[8];
}

// ---------------- mask compaction ----------------
__global__ __launch_bounds__(256)
void compact_mask(const int* __restrict__ mask, int* __restrict__ idx,
                  int* __restrict__ cnt)
{
    int seg = blockIdx.x, b = seg >> 1, half = seg & 1;
    const int* m = mask + b * 2048 + half * 1024;
    int t = threadIdx.x;
    __shared__ int sc[256];
    int v0 = (m[t*4+0] == 0), v1 = (m[t*4+1] == 0);
    int v2 = (m[t*4+2] == 0), v3 = (m[t*4+3] == 0);
    int c = v0 + v1 + v2 + v3;
    sc[t] = c; __syncthreads();
    for (int ofs = 1; ofs < 256; ofs <<= 1) {
        int x = (t >= ofs) ? sc[t - ofs] : 0;
        __syncthreads(); sc[t] += x; __syncthreads();
    }
    int pos = sc[t] - c + seg * 1024;
    if (v0) idx[pos++] = t*4+0;
    if (v1) idx[pos++] = t*4+1;
    if (v2) idx[pos++] = t*4+2;
    if (v3) idx[pos++] = t*4+3;
    if (t == 255) cnt[seg] = sc[255];
}

// ---------------- gather unmasked rows from fp32 x, convert, zero-pad --------
__global__ __launch_bounds__(256)
void gather_cvt(const float* __restrict__ x, const int* __restrict__ idx,
                const int* __restrict__ cnt, ushort* __restrict__ xc)
{
    int seg = blockIdx.x, b = seg >> 1, half = seg & 1;
    int n = cnt[seg];
    int wave = threadIdx.x >> 6, lane = threadIdx.x & 63;
    int j0 = blockIdx.y * 64 + wave * 16;
    for (int i = 0; i < 16; ++i) {
        int j = j0 + i;
        uint4 val = {0u, 0u, 0u, 0u};
        if (j < n) {
            int src = idx[seg * 1024 + j];
            const float* r = x + ((size_t)(b * 2048 + half * 1024 + src)) * 512 + lane * 8;
            float4 a = *(const float4*)r, c4 = *(const float4*)(r + 4);
            ushort tmp[8];
            tmp[0]=f2bf(a.x); tmp[1]=f2bf(a.y); tmp[2]=f2bf(a.z); tmp[3]=f2bf(a.w);
            tmp[4]=f2bf(c4.x); tmp[5]=f2bf(c4.y); tmp[6]=f2bf(c4.z); tmp[7]=f2bf(c4.w);
            val = *(uint4*)tmp;
        }
        *(uint4*)(xc + ((size_t)(seg * 1024 + j)) * 512 + lane * 8) = val;
    }
}

// ---------------- shared GEMM core: C[m][n] = sum_k A[m][k]*B[n][k] ----------
__device__ __forceinline__ void gemm_core(const ushort* __restrict__ A,
                                          const ushort* __restrict__ B,
                                          ushort* __restrict__ C,
                                          int N, int K, int mBase, int nBase)
{
    __shared__ ushort As[128][32];
    __shared__ ushort Bs[128][32];
    const int tid = threadIdx.x;
    const int lane = tid & 63, wave = tid >> 6;
    const int wm = wave >> 1, wn = wave & 1;
    const int lr = lane & 15, lq = lane >> 4;
    const int sr = lane >> 2;
    const int sc = (lane & 3) * 8;

    f32x4 acc[4][4];
    #pragma unroll
    for (int i = 0; i < 4; ++i)
        #pragma unroll
        for (int j = 0; j < 4; ++j) acc[i][j] = (f32x4){0.f, 0.f, 0.f, 0.f};

    for (int k0 = 0; k0 < K; k0 += 32) {
        __syncthreads();
        #pragma unroll
        for (int j = 0; j < 2; ++j) {
            int rbase = wave * 32 + j * 16;
            async_copy16(&As[rbase][0], A + (size_t)(mBase + rbase + sr) * K + k0 + sc);
            async_copy16(&Bs[rbase][0], B + (size_t)(nBase + rbase + sr) * K + k0 + sc);
        }
        __syncthreads();
        bf16x8 af[4], bfr[4];
        #pragma unroll
        for (int mi = 0; mi < 4; ++mi) af[mi] = *(const bf16x8*)&As[wm * 64 + mi * 16 + lr][lq * 8];
        #pragma unroll
        for (int ni = 0; ni < 4; ++ni) bfr[ni] = *(const bf16x8*)&Bs[wn * 64 + ni * 16 + lr][lq * 8];
        #pragma unroll
        for (int mi = 0; mi < 4; ++mi)
            #pragma unroll
            for (int ni = 0; ni < 4; ++ni)
                acc[mi][ni] = __builtin_amdgcn_mfma_f32_16x16x32_bf16(af[mi], bfr[ni], acc[mi][ni], 0, 0, 0);
    }
    #pragma unroll
    for (int mi = 0; mi < 4; ++mi)
        #pragma unroll
        for (int ni = 0; ni < 4; ++ni)
            #pragma unroll
            for (int r = 0; r < 4; ++r) {
                int m = mBase + wm * 64 + mi * 16 + lq * 4 + r;
                int n = nBase + wn * 64 + ni * 16 + lr;
                C[(size_t)m * N + n] = f2bf(acc[mi][ni][r]);
            }
}

__global__ __launch_bounds__(256, 2)
void gemm_m(const ushort* __restrict__ A, const ushort* __restrict__ B,
            ushort* __restrict__ C) {
    gemm_core(A, B, C, 512, 512, blockIdx.y * 128, blockIdx.x * 128);
}

// fused K' and Vt gemms (z-decode); both skip all-pad 128-bands
__global__ __launch_bounds__(256, 2)
void gemm_kv(const ushort* __restrict__ xc, const ushort* __restrict__ Mb,
             ushort* __restrict__ Kc, const ushort* __restrict__ wv,
             ushort* __restrict__ Vtc, const int* __restrict__ cnt)
{
    const ushort *A, *B; ushort* C; int N, mBase, nBase;
    if (blockIdx.z == 0) {
        mBase = blockIdx.y * 128; nBase = blockIdx.x * 128;
        if ((mBase & 1023) >= cnt[mBase >> 10]) return;
        A = xc; B = Mb; C = Kc; N = 512;
    } else {
        mBase = blockIdx.x * 128; nBase = blockIdx.y * 128;
        if ((nBase & 1023) >= cnt[nBase >> 10]) return;
        A = wv; B = xc; C = Vtc; N = 16384;
    }
    gemm_core(A, B, C, N, 512, mBase, nBase);
}

// ---------------- flash attention over COMPACTED keys, no-vmcnt barriers -----
// Q read from fp32 x directly. K'c: [16][1024][512]. Vtc: [512][16*1024].
// Grid (32,8,2). Per tile: Ks<-xfer (K prefetched last iter) | B2(lgkm) |
// V->xfer | QK | softmax | Vs<-xfer | B3(lgkm) | K(kt+1)->xfer | PV | B_top.
// xfer[8] is explicitly time-shared between K and V (register pressure).
__global__ __launch_bounds__(256, 2)
void attn_kernel(const float* __restrict__ xg, const ushort* __restrict__ Kcg,
                 const ushort* __restrict__ Vtcg, const int* __restrict__ cntg,
                 ushort* __restrict__ Pog, float* __restrict__ Mlg)
{
    const int S = 2048;
    const float SL2E = 0.0637587160f;  // (1/sqrt(512)) * log2(e)

    __shared__ ushort Ks[32][548];   // row stride 1096 B
    __shared__ ushort Vs[512][38];   // stride 76 B = 19 dw (odd -> 2-way, free)
    __shared__ ushort Ps[2][32][38];

    const int b = blockIdx.y, qt = blockIdx.x, half = blockIdx.z;
    const int seg = b * 2 + half;
    const int tid = threadIdx.x, lane = tid & 63, wave = tid >> 6;
    const int lr = lane & 15, lq = lane >> 4;
    const int p = wave >> 1, s = wave & 1;
    const int l32 = lane & 31, lh = lane >> 5;

    const int n = cntg[seg];
    const int ntiles = (n + 31) >> 5;

    // Q fragments straight from fp32 x (cvt once per block; cvt_x pass deleted)
    const float* Qp = xg + ((size_t)b * S + qt * 64 + wave * 16 + lr) * 512;
    bf16x8 qf[16];
    #pragma unroll
    for (int c = 0; c < 16; ++c) {
        float4 a = *(const float4*)(Qp + c * 32 + lq * 8);
        float4 d4 = *(const float4*)(Qp + c * 32 + lq * 8 + 4);
        bf16x8 q;
        q[0] = (short)f2bf(a.x);  q[1] = (short)f2bf(a.y);
        q[2] = (short)f2bf(a.z);  q[3] = (short)f2bf(a.w);
        q[4] = (short)f2bf(d4.x); q[5] = (short)f2bf(d4.y);
        q[6] = (short)f2bf(d4.z); q[7] = (short)f2bf(d4.w);
        qf[c] = q;
    }

    f32x16 o[8];
    #pragma unroll
    for (int i = 0; i < 8; ++i)
        #pragma unroll
        for (int r = 0; r < 16; ++r) o[i][r] = 0.f;
    float l_i[4] = {0.f, 0.f, 0.f, 0.f};

    const char* Kseg = (const char*)(Kcg + (size_t)seg * 1024 * 512);
    const char* Vseg = (const char*)Vtcg + (size_t)(seg * 1024) * 2;

    // prologue: K tile 0 into xfer
    uint4 xfer[8];
    #pragma unroll
    for (int i = 0; i < 8; ++i) {
        int off = i * 4096 + tid * 16, row = off >> 10, col = off & 1023;
        xfer[i] = *(const uint4*)(Kseg + (size_t)row * 1024 + col);
    }

    for (int kt = 0; kt < ntiles; ++kt) {
        const int key0 = kt * 32;
        BAR_NONE();   // B_top: prev PV reads retired (lgkm waits already forced)
        // Ks <- xfer (compiler inserts vmcnt wait; K loads had the PV phase)
        #pragma unroll
        for (int i = 0; i < 8; ++i) {
            int off = i * 4096 + tid * 16, row = off >> 10, col = off & 1023;
            *(uint4*)((char*)Ks + (size_t)row * 1096 + col) = xfer[i];
        }
        BAR_LGKM();   // B2: Ks visible; no global drain
        // V tile -> xfer (in flight across QK+softmax)
        {
            const char* gV = Vseg + (size_t)key0 * 2;
            #pragma unroll
            for (int i = 0; i < 8; ++i) {
                int off = i * 4096 + tid * 16, row = off >> 6, col = off & 63;
                xfer[i] = *(const uint4*)(gV + (size_t)row * 32768 + col);
            }
        }
        const bool va0 = (key0 + lr) < n;
        const bool va1 = (key0 + 16 + lr) < n;
        // S = Q Ktile^T
        f32x4 sf0 = (f32x4){0.f,0.f,0.f,0.f}, sf1 = (f32x4){0.f,0.f,0.f,0.f};
        #pragma unroll
        for (int ks = 0; ks < 16; ++ks) {
            bf16x8 kf0 = *(const bf16x8*)&Ks[lr][ks * 32 + lq * 8];
            bf16x8 kf1 = *(const bf16x8*)&Ks[16 + lr][ks * 32 + lq * 8];
            sf0 = __builtin_amdgcn_mfma_f32_16x16x32_bf16(qf[ks], kf0, sf0, 0, 0, 0);
            sf1 = __builtin_amdgcn_mfma_f32_16x16x32_bf16(qf[ks], kf1, sf1, 0, 0, 0);
        }
        // static-max softmax
        #pragma unroll
        for (int r = 0; r < 4; ++r) {
            float p0 = va0 ? exp2f(fmaf(sf0[r], SL2E, -8.f)) : 0.f;
            float p1 = va1 ? exp2f(fmaf(sf1[r], SL2E, -8.f)) : 0.f;
            l_i[r] += p0 + p1;
            Ps[p][16 * s + lq * 4 + r][lr]      = f2bf(p0);
            Ps[p][16 * s + lq * 4 + r][16 + lr] = f2bf(p1);
        }
        // Vs <- xfer (vmcnt wait here; V had the whole QK phase)
        #pragma unroll
        for (int i = 0; i < 8; ++i) {
            int off = i * 4096 + tid * 16, row = off >> 6, col = off & 63;
            *(uint4*)((char*)Vs + (size_t)row * 76 + col) = xfer[i];
        }
        BAR_LGKM();   // B3: Ps + Vs visible; no global drain
        bf16x8 pA0 = *(const bf16x8*)&Ps[p][l32][lh * 8];
        bf16x8 pA1 = *(const bf16x8*)&Ps[p][l32][16 + lh * 8];
        // K prefetch for next tile (hidden behind PV + B_top)
        if (kt + 1 < ntiles) {
            const char* gK = Kseg + (size_t)(key0 + 32) * 1024;
            #pragma unroll
            for (int i = 0; i < 8; ++i) {
                int off = i * 4096 + tid * 16, row = off >> 10, col = off & 1023;
                xfer[i] = *(const uint4*)(gK + (size_t)row * 1024 + col);
            }
        }
        // O += P(32x32) @ V(32 x d256), d-range by s
        #pragma unroll
        for (int dt = 0; dt < 8; ++dt) {
            int d = s * 256 + dt * 32 + l32;
            bf16x8 v0 = *(const bf16x8*)&Vs[d][lh * 8];
            bf16x8 v1 = *(const bf16x8*)&Vs[d][16 + lh * 8];
            o[dt] = __builtin_amdgcn_mfma_f32_32x32x16_bf16(pA0, v0, o[dt], 0, 0, 0);
            o[dt] = __builtin_amdgcn_mfma_f32_32x32x16_bf16(pA1, v1, o[dt], 0, 0, 0);
        }
    }
    // final cross-lane l reduction
    #pragma unroll
    for (int r = 0; r < 4; ++r)
        #pragma unroll
        for (int off = 1; off < 16; off <<= 1)
            l_i[r] += __shfl_xor(l_i[r], off, 16);
    const size_t growbase = (size_t)half * 16384 + (size_t)b * S + qt * 64;
    if (lr == 0) {
        #pragma unroll
        for (int r = 0; r < 4; ++r)
            Mlg[growbase + wave * 16 + lq * 4 + r] = l_i[r];
    }
    // unnormalized partial O: pair rows [32p,32p+32), cols [256s,256s+256)
    ushort* Pop = Pog + (growbase + p * 32) * 512;
    #pragma unroll
    for (int dt = 0; dt < 8; ++dt) {
        int ocol = s * 256 + dt * 32 + l32;
        #pragma unroll
        for (int r = 0; r < 16; ++r) {
            int orow = (r & 3) + 8 * (r >> 2) + 4 * lh;
            Pop[(size_t)orow * 512 + ocol] = f2bf(o[dt][r]);
        }
    }
}

// ---------------- combine the two key-halves ----------------
__global__ __launch_bounds__(256)
void combine_kernel(const ushort* __restrict__ Po, const float* __restrict__ Ml,
                    float* __restrict__ out)
{
    int i = (blockIdx.x * 256 + threadIdx.x) * 4;
    int row = i >> 9;
    float l = Ml[row] + Ml[16384 + row];
    float s = l > 0.f ? 1.f / l : 0.f;
    ushort4 p1 = *(const ushort4*)(Po + i);
    ushort4 p2 = *(const ushort4*)(Po + 8388608 + i);
    float4 o;
    o.x = (bf2f(p1.x) + bf2f(p2.x)) * s;
    o.y = (bf2f(p1.y) + bf2f(p2.y)) * s;
    o.z = (bf2f(p1.z) + bf2f(p2.z)) * s;
    o.w = (bf2f(p1.w) + bf2f(p2.w)) * s;
    *(float4*)(out + i) = o;
}

extern "C" void kernel_launch(void* const* d_in, const int* in_sizes, int n_in,
                              void* d_out, int out_size, void* d_ws, size_t ws_size,
                              hipStream_t stream) {
    const float* x  = (const float*)d_in[0];
    // d_in[1] = bias: additive scalar on all logits -> softmax shift-invariant -> no-op
    const int* mask = (const int*)d_in[2];
    const float* Wq = (const float*)d_in[3];
    const float* Wk = (const float*)d_in[4];
    const float* Wv = (const float*)d_in[5];
    float* out = (float*)d_out;

    // Workspace (ushort units).
    //  Po  [0, 16777216)  phase 2; Mb [0,262144) + idx [262144,294912) live
    //                     only through gemm_kv (dead before attn writes Po)
    //  wqT [16777216, +262144) | wkT | wvb
    //  xc  [17563648, 25952256)
    //  Kc  [25952256, 34340864)
    //  Vtc [34340864, 42729472)
    //  Ml  [42729472, 42795008)
    //  cnt [42795008, 42795040)
    ushort* ws   = (ushort*)d_ws;
    ushort* Pob  = ws;
    ushort* Mb   = ws;
    int*    idxb = (int*)(ws + 262144);
    ushort* wqT  = ws + 16777216;
    ushort* wkT  = wqT + 262144;
    ushort* wvb  = wkT + 262144;
    ushort* xc   = ws + 17563648;
    ushort* Kc   = ws + 25952256;
    ushort* Vtc  = ws + 34340864;
    float*  Mlb  = (float*)(ws + 42729472);
    int*    cntb = (int*)(ws + 42795008);

    cvt_wT<<<dim3(8, 8, 2), 256, 0, stream>>>(Wq, Wk, wqT, wkT);
    cvt_f32_bf16<<<256, 256, 0, stream>>>(Wv, wvb, 262144);
    compact_mask<<<16, 256, 0, stream>>>(mask, idxb, cntb);
    gather_cvt<<<dim3(16, 16), 256, 0, stream>>>(x, idxb, cntb, xc);
    // M = Wq^T Wk
    gemm_m<<<dim3(4, 4), 256, 0, stream>>>(wqT, wkT, Mb);
    // K'c = xc M^T  and  Vtc = Wv xc^T  (fused, pad-band skip)
    gemm_kv<<<dim3(4, 128, 2), 256, 0, stream>>>(xc, Mb, Kc, wvb, Vtc, cntb);
    attn_kernel<<<dim3(32, 8, 2), 256, 0, stream>>>(x, Kc, Vtc, cntb, Pob, Mlb);
    combine_kernel<<<8192, 256, 0, stream>>>(Pob, Mlb, out);
}

// Round 10
// 229.038 us; speedup vs baseline: 1.7933x; 1.7933x over previous
//
#include <hip/hip_runtime.h>

typedef short bf16x8 __attribute__((ext_vector_type(8)));
typedef float f32x4 __attribute__((ext_vector_type(4)));
typedef float f32x16 __attribute__((ext_vector_type(16)));

__device__ __forceinline__ ushort f2bf(float f) {
    union { float f; unsigned u; } v; v.f = f;
    unsigned r = (v.u + 0x7fffu + ((v.u >> 16) & 1u)) >> 16;
    return (ushort)r;
}
__device__ __forceinline__ float bf2f(ushort u) {
    union { unsigned u; float f; } v; v.u = ((unsigned)u) << 16;
    return v.f;
}
__device__ __forceinline__ void async_copy16(void* lds, const void* g) {
    __builtin_amdgcn_global_load_lds(
        (const __attribute__((address_space(1))) unsigned*)g,
        (__attribute__((address_space(3))) unsigned*)lds, 16, 0, 0);
}

// ---------------- fused prep: cvt_x | cvt_wT(Wq,Wk) | cvt(Wv) | compact ------
// grid 8592: [0,8192) cvt x; [8192,8320) transpose-cvt Wq/Wk; [8320,8576) cvt
// Wv; [8576,8592) per-segment mask compaction. All branches block-uniform.
__global__ __launch_bounds__(256)
void prep_kernel(const float* __restrict__ x, const float* __restrict__ Wq,
                 const float* __restrict__ Wk, const float* __restrict__ Wv,
                 const int* __restrict__ mask,
                 ushort* __restrict__ xb, ushort* __restrict__ wqT,
                 ushort* __restrict__ wkT, ushort* __restrict__ wvb,
                 int* __restrict__ idx, int* __restrict__ cnt)
{
    const int bid = blockIdx.x, t = threadIdx.x;
    if (bid < 8192) {                       // x fp32 -> bf16
        int i = (bid * 256 + t) * 4;
        float4 v = *(const float4*)(x + i);
        ushort4 o;
        o.x = f2bf(v.x); o.y = f2bf(v.y); o.z = f2bf(v.z); o.w = f2bf(v.w);
        *(ushort4*)(xb + i) = o;
    } else if (bid < 8320) {                // Wq/Wk transpose-convert
        __shared__ ushort T[64][72];
        int r = bid - 8192;
        const int z = r >> 6; r &= 63;
        const float* in = z ? Wk : Wq;
        ushort* out     = z ? wkT : wqT;
        const int r0 = (r >> 3) * 64, c0 = (r & 7) * 64;
        const int rr = t >> 3, cc8 = (t & 7) * 8;
        #pragma unroll
        for (int pass = 0; pass < 2; ++pass) {
            int rw = rr + pass * 32;
            float4 a = *(const float4*)(in + (size_t)(r0 + rw) * 512 + c0 + cc8);
            float4 bq = *(const float4*)(in + (size_t)(r0 + rw) * 512 + c0 + cc8 + 4);
            T[rw][cc8+0]=f2bf(a.x);  T[rw][cc8+1]=f2bf(a.y);  T[rw][cc8+2]=f2bf(a.z);  T[rw][cc8+3]=f2bf(a.w);
            T[rw][cc8+4]=f2bf(bq.x); T[rw][cc8+5]=f2bf(bq.y); T[rw][cc8+6]=f2bf(bq.z); T[rw][cc8+7]=f2bf(bq.w);
        }
        __syncthreads();
        const int c = t >> 2, seg = (t & 3) * 16;
        ushort tmp[16];
        #pragma unroll
        for (int j = 0; j < 16; ++j) tmp[j] = T[seg + j][c];
        *(uint4*)(out + (size_t)(c0 + c) * 512 + r0 + seg)     = *(uint4*)&tmp[0];
        *(uint4*)(out + (size_t)(c0 + c) * 512 + r0 + seg + 8) = *(uint4*)&tmp[8];
    } else if (bid < 8576) {                // Wv fp32 -> bf16
        int i = ((bid - 8320) * 256 + t) * 4;
        float4 v = *(const float4*)(Wv + i);
        ushort4 o;
        o.x = f2bf(v.x); o.y = f2bf(v.y); o.z = f2bf(v.z); o.w = f2bf(v.w);
        *(ushort4*)(wvb + i) = o;
    } else {                                // mask compaction
        __shared__ int sc[256];
        int seg = bid - 8576, b = seg >> 1, half = seg & 1;
        const int* m = mask + b * 2048 + half * 1024;
        int v0 = (m[t*4+0] == 0), v1 = (m[t*4+1] == 0);
        int v2 = (m[t*4+2] == 0), v3 = (m[t*4+3] == 0);
        int c = v0 + v1 + v2 + v3;
        sc[t] = c; __syncthreads();
        for (int ofs = 1; ofs < 256; ofs <<= 1) {
            int xx = (t >= ofs) ? sc[t - ofs] : 0;
            __syncthreads(); sc[t] += xx; __syncthreads();
        }
        int pos = sc[t] - c + seg * 1024;
        if (v0) idx[pos++] = t*4+0;
        if (v1) idx[pos++] = t*4+1;
        if (v2) idx[pos++] = t*4+2;
        if (v3) idx[pos++] = t*4+3;
        if (t == 255) cnt[seg] = sc[255];
    }
}

// ---------------- gather unmasked rows from fp32 x, convert, zero-pad --------
__global__ __launch_bounds__(256)
void gather_cvt(const float* __restrict__ x, const int* __restrict__ idx,
                const int* __restrict__ cnt, ushort* __restrict__ xc)
{
    int seg = blockIdx.x, b = seg >> 1, half = seg & 1;
    int n = cnt[seg];
    int wave = threadIdx.x >> 6, lane = threadIdx.x & 63;
    int j0 = blockIdx.y * 64 + wave * 16;
    for (int i = 0; i < 16; ++i) {
        int j = j0 + i;
        uint4 val = {0u, 0u, 0u, 0u};
        if (j < n) {
            int src = idx[seg * 1024 + j];
            const float* r = x + ((size_t)(b * 2048 + half * 1024 + src)) * 512 + lane * 8;
            float4 a = *(const float4*)r, c4 = *(const float4*)(r + 4);
            ushort tmp[8];
            tmp[0]=f2bf(a.x); tmp[1]=f2bf(a.y); tmp[2]=f2bf(a.z); tmp[3]=f2bf(a.w);
            tmp[4]=f2bf(c4.x); tmp[5]=f2bf(c4.y); tmp[6]=f2bf(c4.z); tmp[7]=f2bf(c4.w);
            val = *(uint4*)tmp;
        }
        *(uint4*)(xc + ((size_t)(seg * 1024 + j)) * 512 + lane * 8) = val;
    }
}

// ---------------- shared GEMM core: C[m][n] = sum_k A[m][k]*B[n][k] ----------
__device__ __forceinline__ void gemm_core(const ushort* __restrict__ A,
                                          const ushort* __restrict__ B,
                                          ushort* __restrict__ C,
                                          int N, int K, int mBase, int nBase)
{
    __shared__ ushort As[128][32];
    __shared__ ushort Bs[128][32];
    const int tid = threadIdx.x;
    const int lane = tid & 63, wave = tid >> 6;
    const int wm = wave >> 1, wn = wave & 1;
    const int lr = lane & 15, lq = lane >> 4;
    const int sr = lane >> 2;
    const int sc = (lane & 3) * 8;

    f32x4 acc[4][4];
    #pragma unroll
    for (int i = 0; i < 4; ++i)
        #pragma unroll
        for (int j = 0; j < 4; ++j) acc[i][j] = (f32x4){0.f, 0.f, 0.f, 0.f};

    for (int k0 = 0; k0 < K; k0 += 32) {
        __syncthreads();
        #pragma unroll
        for (int j = 0; j < 2; ++j) {
            int rbase = wave * 32 + j * 16;
            async_copy16(&As[rbase][0], A + (size_t)(mBase + rbase + sr) * K + k0 + sc);
            async_copy16(&Bs[rbase][0], B + (size_t)(nBase + rbase + sr) * K + k0 + sc);
        }
        __syncthreads();
        bf16x8 af[4], bfr[4];
        #pragma unroll
        for (int mi = 0; mi < 4; ++mi) af[mi] = *(const bf16x8*)&As[wm * 64 + mi * 16 + lr][lq * 8];
        #pragma unroll
        for (int ni = 0; ni < 4; ++ni) bfr[ni] = *(const bf16x8*)&Bs[wn * 64 + ni * 16 + lr][lq * 8];
        #pragma unroll
        for (int mi = 0; mi < 4; ++mi)
            #pragma unroll
            for (int ni = 0; ni < 4; ++ni)
                acc[mi][ni] = __builtin_amdgcn_mfma_f32_16x16x32_bf16(af[mi], bfr[ni], acc[mi][ni], 0, 0, 0);
    }
    #pragma unroll
    for (int mi = 0; mi < 4; ++mi)
        #pragma unroll
        for (int ni = 0; ni < 4; ++ni)
            #pragma unroll
            for (int r = 0; r < 4; ++r) {
                int m = mBase + wm * 64 + mi * 16 + lq * 4 + r;
                int n = nBase + wn * 64 + ni * 16 + lr;
                C[(size_t)m * N + n] = f2bf(acc[mi][ni][r]);
            }
}

__global__ __launch_bounds__(256, 2)
void gemm_m(const ushort* __restrict__ A, const ushort* __restrict__ B,
            ushort* __restrict__ C) {
    gemm_core(A, B, C, 512, 512, blockIdx.y * 128, blockIdx.x * 128);
}

// fused K' and Vt gemms (z-decode); both skip all-pad 128-bands
__global__ __launch_bounds__(256, 2)
void gemm_kv(const ushort* __restrict__ xc, const ushort* __restrict__ Mb,
             ushort* __restrict__ Kc, const ushort* __restrict__ wv,
             ushort* __restrict__ Vtc, const int* __restrict__ cnt)
{
    const ushort *A, *B; ushort* C; int N, mBase, nBase;
    if (blockIdx.z == 0) {
        mBase = blockIdx.y * 128; nBase = blockIdx.x * 128;
        if ((mBase & 1023) >= cnt[mBase >> 10]) return;
        A = xc; B = Mb; C = Kc; N = 512;
    } else {
        mBase = blockIdx.x * 128; nBase = blockIdx.y * 128;
        if ((nBase & 1023) >= cnt[nBase >> 10]) return;
        A = wv; B = xc; C = Vtc; N = 16384;
    }
    gemm_core(A, B, C, N, 512, mBase, nBase);
}

// ---------------- flash attention over COMPACTED keys (R8-exact) -------------
// Q = xb [B*S][512] bf16. K'c: [16][1024][512]. Vtc: [512][16*1024].
// Grid (32,8,2). 32-key tiles, pair-split PV (mfma 32x32x16), static-max.
__global__ __launch_bounds__(256, 2)
void attn_kernel(const ushort* __restrict__ Qg, const ushort* __restrict__ Kcg,
                 const ushort* __restrict__ Vtcg, const int* __restrict__ cntg,
                 ushort* __restrict__ Pog, float* __restrict__ Mlg)
{
    const int S = 2048;
    const float SL2E = 0.0637587160f;  // (1/sqrt(512)) * log2(e)

    __shared__ ushort Ks[32][548];
    __shared__ ushort Vs[512][36];
    __shared__ ushort Ps[2][32][36];

    const int b = blockIdx.y, qt = blockIdx.x, half = blockIdx.z;
    const int seg = b * 2 + half;
    const int tid = threadIdx.x, lane = tid & 63, wave = tid >> 6;
    const int lr = lane & 15, lq = lane >> 4;
    const int p = wave >> 1, s = wave & 1;
    const int l32 = lane & 31, lh = lane >> 5;

    const int n = cntg[seg];
    const int ntiles = (n + 31) >> 5;

    const ushort* Qp = Qg + ((size_t)b * S + qt * 64 + wave * 16 + lr) * 512;
    bf16x8 qf[16];
    #pragma unroll
    for (int c = 0; c < 16; ++c) qf[c] = *(const bf16x8*)(Qp + c * 32 + lq * 8);

    f32x16 o[8];
    #pragma unroll
    for (int i = 0; i < 8; ++i)
        #pragma unroll
        for (int r = 0; r < 16; ++r) o[i][r] = 0.f;
    float l_i[4] = {0.f, 0.f, 0.f, 0.f};

    const char* Kseg = (const char*)(Kcg + (size_t)seg * 1024 * 512);
    const char* Vseg = (const char*)Vtcg + (size_t)(seg * 1024) * 2;

    for (int kt = 0; kt < ntiles; ++kt) {
        const int key0 = kt * 32;
        __syncthreads();
        {
            const char* gK = Kseg + (size_t)key0 * 1024;
            #pragma unroll
            for (int i = 0; i < 8; ++i) {
                int row = wave * 8 + i;
                async_copy16(&Ks[row][0], gK + (size_t)row * 1024 + lane * 16);
            }
        }
        const bool va0 = (key0 + lr) < n;
        const bool va1 = (key0 + 16 + lr) < n;
        __syncthreads();
        uint4 vreg[8];
        {
            const char* gV = Vseg + (size_t)key0 * 2;
            #pragma unroll
            for (int i = 0; i < 8; ++i) {
                int off = i * 4096 + tid * 16;
                int row = off >> 6, col = off & 63;
                vreg[i] = *(const uint4*)(gV + (size_t)row * 32768 + col);
            }
        }
        f32x4 sf0 = (f32x4){0.f,0.f,0.f,0.f}, sf1 = (f32x4){0.f,0.f,0.f,0.f};
        #pragma unroll
        for (int ks = 0; ks < 16; ++ks) {
            bf16x8 kf0 = *(const bf16x8*)&Ks[lr][ks * 32 + lq * 8];
            bf16x8 kf1 = *(const bf16x8*)&Ks[16 + lr][ks * 32 + lq * 8];
            sf0 = __builtin_amdgcn_mfma_f32_16x16x32_bf16(qf[ks], kf0, sf0, 0, 0, 0);
            sf1 = __builtin_amdgcn_mfma_f32_16x16x32_bf16(qf[ks], kf1, sf1, 0, 0, 0);
        }
        #pragma unroll
        for (int r = 0; r < 4; ++r) {
            float p0 = va0 ? exp2f(fmaf(sf0[r], SL2E, -8.f)) : 0.f;
            float p1 = va1 ? exp2f(fmaf(sf1[r], SL2E, -8.f)) : 0.f;
            l_i[r] += p0 + p1;
            Ps[p][16 * s + lq * 4 + r][lr]      = f2bf(p0);
            Ps[p][16 * s + lq * 4 + r][16 + lr] = f2bf(p1);
        }
        #pragma unroll
        for (int i = 0; i < 8; ++i) {
            int off = i * 4096 + tid * 16;
            int row = off >> 6, col = off & 63;
            *(uint4*)((char*)Vs + row * 72 + col) = vreg[i];
        }
        __syncthreads();
        bf16x8 pA0 = *(const bf16x8*)&Ps[p][l32][lh * 8];
        bf16x8 pA1 = *(const bf16x8*)&Ps[p][l32][16 + lh * 8];
        #pragma unroll
        for (int dt = 0; dt < 8; ++dt) {
            int d = s * 256 + dt * 32 + l32;
            bf16x8 v0 = *(const bf16x8*)&Vs[d][lh * 8];
            bf16x8 v1 = *(const bf16x8*)&Vs[d][16 + lh * 8];
            o[dt] = __builtin_amdgcn_mfma_f32_32x32x16_bf16(pA0, v0, o[dt], 0, 0, 0);
            o[dt] = __builtin_amdgcn_mfma_f32_32x32x16_bf16(pA1, v1, o[dt], 0, 0, 0);
        }
    }
    #pragma unroll
    for (int r = 0; r < 4; ++r)
        #pragma unroll
        for (int off = 1; off < 16; off <<= 1)
            l_i[r] += __shfl_xor(l_i[r], off, 16);
    const size_t growbase = (size_t)half * 16384 + (size_t)b * S + qt * 64;
    if (lr == 0) {
        #pragma unroll
        for (int r = 0; r < 4; ++r)
            Mlg[growbase + wave * 16 + lq * 4 + r] = l_i[r];
    }
    ushort* Pop = Pog + (growbase + p * 32) * 512;
    #pragma unroll
    for (int dt = 0; dt < 8; ++dt) {
        int ocol = s * 256 + dt * 32 + l32;
        #pragma unroll
        for (int r = 0; r < 16; ++r) {
            int orow = (r & 3) + 8 * (r >> 2) + 4 * lh;
            Pop[(size_t)orow * 512 + ocol] = f2bf(o[dt][r]);
        }
    }
}

// ---------------- combine the two key-halves ----------------
__global__ __launch_bounds__(256)
void combine_kernel(const ushort* __restrict__ Po, const float* __restrict__ Ml,
                    float* __restrict__ out)
{
    int i = (blockIdx.x * 256 + threadIdx.x) * 4;
    int row = i >> 9;
    float l = Ml[row] + Ml[16384 + row];
    float s = l > 0.f ? 1.f / l : 0.f;
    ushort4 p1 = *(const ushort4*)(Po + i);
    ushort4 p2 = *(const ushort4*)(Po + 8388608 + i);
    float4 o;
    o.x = (bf2f(p1.x) + bf2f(p2.x)) * s;
    o.y = (bf2f(p1.y) + bf2f(p2.y)) * s;
    o.z = (bf2f(p1.z) + bf2f(p2.z)) * s;
    o.w = (bf2f(p1.w) + bf2f(p2.w)) * s;
    *(float4*)(out + i) = o;
}

extern "C" void kernel_launch(void* const* d_in, const int* in_sizes, int n_in,
                              void* d_out, int out_size, void* d_ws, size_t ws_size,
                              hipStream_t stream) {
    const float* x  = (const float*)d_in[0];
    // d_in[1] = bias: additive scalar on all logits -> softmax shift-invariant -> no-op
    const int* mask = (const int*)d_in[2];
    const float* Wq = (const float*)d_in[3];
    const float* Wk = (const float*)d_in[4];
    const float* Wv = (const float*)d_in[5];
    float* out = (float*)d_out;

    // Workspace (ushort units).
    //  xb  [0,        8388608)   bf16 x — live through attn (Q source)
    //  wst [8388608,  9175040)   wqT | wkT | wvb
    //  xc  [9175040, 17563648)   phase 1 (dead after gemm_kv)
    //  Po  [9175040, 25952256)   phase 2 (overlaps xc+Mb+idx, all dead)
    //  Mb  [17563648,17825792)
    //  idx [17825792,17858560)
    //  Kc  [25952256,34340864)
    //  Vtc [34340864,42729472)
    //  Ml  [42729472,42795008)
    //  cnt [42795008,42795040)
    ushort* ws   = (ushort*)d_ws;
    ushort* xb   = ws;
    ushort* wqT  = ws + 8388608;
    ushort* wkT  = wqT + 262144;
    ushort* wvb  = wkT + 262144;
    ushort* xc   = ws + 9175040;
    ushort* Pob  = ws + 9175040;
    ushort* Mb   = ws + 17563648;
    int*    idxb = (int*)(ws + 17825792);
    ushort* Kc   = ws + 25952256;
    ushort* Vtc  = ws + 34340864;
    float*  Mlb  = (float*)(ws + 42729472);
    int*    cntb = (int*)(ws + 42795008);

    prep_kernel<<<8592, 256, 0, stream>>>(x, Wq, Wk, Wv, mask,
                                          xb, wqT, wkT, wvb, idxb, cntb);
    gather_cvt<<<dim3(16, 16), 256, 0, stream>>>(x, idxb, cntb, xc);
    // M = Wq^T Wk
    gemm_m<<<dim3(4, 4), 256, 0, stream>>>(wqT, wkT, Mb);
    // K'c = xc M^T  and  Vtc = Wv xc^T  (fused, pad-band skip)
    gemm_kv<<<dim3(4, 128, 2), 256, 0, stream>>>(xc, Mb, Kc, wvb, Vtc, cntb);
    attn_kernel<<<dim3(32, 8, 2), 256, 0, stream>>>(xb, Kc, Vtc, cntb, Pob, Mlb);
    combine_kernel<<<8192, 256, 0, stream>>>(Pob, Mlb, out);
}